// Round 6
// baseline (190.118 us; speedup 1.0000x reference)
//
#include <hip/hip_runtime.h>
#include <math.h>

#define NSRC 2048
#define HID  1024
#define FSTR 72     // LDS row stride (bf16) for fourier stage
#define NBLK 512    // persistent grid: 2 blocks/CU on 256 CUs (co-resident)
#define NTHR 256

typedef __bf16 bf16_t;
typedef bf16_t bf16x8 __attribute__((ext_vector_type(8)));
typedef bf16_t bf16x4 __attribute__((ext_vector_type(4)));
typedef float  f32x4  __attribute__((ext_vector_type(4)));
typedef unsigned long long u64;

__device__ __forceinline__ float gelu_f(float x) {
  float u = 0.7978845608028654f * x * (1.0f + 0.044715f * x * x);
  return 0.5f * x * (1.0f + tanhf(u));
}

// ---- agent-coherent (sc1, MALL) access helpers ----
// All cross-block intermediates flow through these; they are coherent at the
// device point, so NO buffer_wbl2/buffer_inv is needed anywhere. Every atomic
// is 32- or 64-bit (AMDGPU-native widths).
__device__ __forceinline__ u64 ald64(const void* p) {
  return __hip_atomic_load((const u64*)p, __ATOMIC_RELAXED,
                           __HIP_MEMORY_SCOPE_AGENT);
}
__device__ __forceinline__ void ast64(void* p, u64 v) {
  __hip_atomic_store((u64*)p, v, __ATOMIC_RELAXED, __HIP_MEMORY_SCOPE_AGENT);
}
__device__ __forceinline__ void ast32(void* p, unsigned v) {
  __hip_atomic_store((unsigned*)p, v, __ATOMIC_RELAXED,
                     __HIP_MEMORY_SCOPE_AGENT);
}
__device__ __forceinline__ void astf(float* p, float v) {
  __hip_atomic_store(p, v, __ATOMIC_RELAXED, __HIP_MEMORY_SCOPE_AGENT);
}
__device__ __forceinline__ float aldf(const float* p) {
  return __hip_atomic_load(p, __ATOMIC_RELAXED, __HIP_MEMORY_SCOPE_AGENT);
}
__device__ __forceinline__ bf16x8 ald128(const void* p) {
  union { u64 u[2]; bf16x8 v; } x;
  x.u[0] = ald64(p);
  x.u[1] = ald64((const char*)p + 8);
  return x.v;
}
__device__ __forceinline__ unsigned short b2s(bf16_t b) {
  union { bf16_t b; unsigned short s; } u; u.b = b; return u.s;
}
__device__ __forceinline__ bf16x8 cvt8(f32x4 a, f32x4 b) {
  bf16x8 o = {(bf16_t)a[0], (bf16_t)a[1], (bf16_t)a[2], (bf16_t)a[3],
              (bf16_t)b[0], (bf16_t)b[1], (bf16_t)b[2], (bf16_t)b[3]};
  return o;
}

// Bare counter barrier: no cache ops. Stores before it are sc1 (at the
// coherence point once vmcnt drains, which __syncthreads guarantees).
__device__ __forceinline__ void grid_bar(unsigned* cnt, unsigned target) {
  __syncthreads();   // drains vmcnt: all sc1 stores complete before arrive
  if (threadIdx.x == 0) {
    __hip_atomic_fetch_add(cnt, 1u, __ATOMIC_RELAXED, __HIP_MEMORY_SCOPE_AGENT);
    while (__hip_atomic_load(cnt, __ATOMIC_RELAXED, __HIP_MEMORY_SCOPE_AGENT) <
           target)
      __builtin_amdgcn_s_sleep(2);
  }
  __syncthreads();
}

// C = gelu(A @ Bf^T + bias). A (2048,1024) bf16 via sc1 loads; Bf (1024,1024)
// fp32 READ-ONLY INPUT via plain cached loads + on-the-fly bf16 convert in
// staging (numerically identical cast to the old precomputed W2b/W3b).
// BM=BN=64, BK=64, rolling-register prefetch (issued BEFORE ds_writes) +
// LDS double-buffer, one barrier per k-step, XOR bank swizzle.
// C-writes: lane-pair shfl packs 2 bf16 -> one 32-bit sc1 store (even lanes).
template <bool WRITE_C, bool COLSUM>
__device__ __forceinline__ void gemm_stage(
    const bf16_t* __restrict__ A, const float* __restrict__ Bf,
    const float* __restrict__ bias, bf16_t* __restrict__ C,
    float* __restrict__ hsum, bf16_t* Asb, bf16_t* Bsb, int tm, int tn) {
  const int K = 1024, NDIM = 1024;
  const int tid  = threadIdx.x;
  const int wave = tid >> 6;
  const int lane = tid & 63;
  const int wm = (wave & 1) * 32;
  const int wn = (wave >> 1) * 32;

  const int row0 = tid >> 3;           // 0..31
  const int pc   = tid & 7;
  const int lc   = pc ^ (row0 & 7);
  const bf16_t* gA = A + (size_t)(tm + row0) * K + lc * 8;
  const float*  gB = Bf + (size_t)(tn + row0) * K + lc * 8;

  const int col15 = lane & 15;
  const int quad  = lane >> 4;
  const int rsw   = col15 & 7;
  f32x4 acc[2][2] = {};

  // prologue: k0=0 tile into regs
  bf16x8 ra0 = ald128(gA);
  bf16x8 ra1 = ald128(gA + (size_t)32 * K);
  f32x4 rb00 = *(const f32x4*)(gB);
  f32x4 rb01 = *(const f32x4*)(gB + 4);
  f32x4 rb10 = *(const f32x4*)(gB + (size_t)32 * K);
  f32x4 rb11 = *(const f32x4*)(gB + (size_t)32 * K + 4);

#define COMPUTE_TILE(b)                                                        \
  do {                                                                         \
    _Pragma("unroll")                                                          \
    for (int s = 0; s < 2; ++s) {                                              \
      const int pck = (s * 4 + quad) ^ rsw;                                    \
      bf16x8 a0 = *(const bf16x8*)(&Asb[(b)*4096 + (wm + col15) * 64 + pck * 8]);      \
      bf16x8 a1 = *(const bf16x8*)(&Asb[(b)*4096 + (wm + 16 + col15) * 64 + pck * 8]); \
      bf16x8 b0 = *(const bf16x8*)(&Bsb[(b)*4096 + (wn + col15) * 64 + pck * 8]);      \
      bf16x8 b1 = *(const bf16x8*)(&Bsb[(b)*4096 + (wn + 16 + col15) * 64 + pck * 8]); \
      acc[0][0] = __builtin_amdgcn_mfma_f32_16x16x32_bf16(a0, b0, acc[0][0], 0, 0, 0); \
      acc[0][1] = __builtin_amdgcn_mfma_f32_16x16x32_bf16(a0, b1, acc[0][1], 0, 0, 0); \
      acc[1][0] = __builtin_amdgcn_mfma_f32_16x16x32_bf16(a1, b0, acc[1][0], 0, 0, 0); \
      acc[1][1] = __builtin_amdgcn_mfma_f32_16x16x32_bf16(a1, b1, acc[1][1], 0, 0, 0); \
    }                                                                          \
  } while (0)

  for (int k0 = 0; k0 < K; k0 += 64) {
    const int buf = (k0 >> 6) & 1;
    __syncthreads();   // prev compute of `buf` done across all waves
    bf16x8 na0, na1; f32x4 nb00, nb01, nb10, nb11;
    const bool more = (k0 + 64 < K);
    if (more) {        // issue next-tile loads BEFORE ds_writes (rolling regs)
      na0  = ald128(gA + k0 + 64);
      na1  = ald128(gA + (size_t)32 * K + k0 + 64);
      nb00 = *(const f32x4*)(gB + k0 + 64);
      nb01 = *(const f32x4*)(gB + k0 + 68);
      nb10 = *(const f32x4*)(gB + (size_t)32 * K + k0 + 64);
      nb11 = *(const f32x4*)(gB + (size_t)32 * K + k0 + 68);
    }
    *(bf16x8*)(&Asb[buf * 4096 + tid * 8])         = ra0;
    *(bf16x8*)(&Asb[buf * 4096 + (tid + 256) * 8]) = ra1;
    *(bf16x8*)(&Bsb[buf * 4096 + tid * 8])         = cvt8(rb00, rb01);
    *(bf16x8*)(&Bsb[buf * 4096 + (tid + 256) * 8]) = cvt8(rb10, rb11);
    if (more) {
      ra0 = na0; ra1 = na1;
      rb00 = nb00; rb01 = nb01; rb10 = nb10; rb11 = nb11;
    }
    if (k0 > 0) COMPUTE_TILE(buf ^ 1);
  }
  __syncthreads();
  COMPUTE_TILE(1);     // 16 tiles, last buf = 15 & 1 = 1
#undef COMPUTE_TILE

  const int rq = quad * 4;
#pragma unroll
  for (int j = 0; j < 2; ++j) {
    const int col = tn + wn + j * 16 + col15;
    const float bj = bias[col];
    float cs = 0.0f;
#pragma unroll
    for (int i = 0; i < 2; ++i) {
      const int rbase = tm + wm + i * 16 + rq;
#pragma unroll
      for (int p = 0; p < 4; ++p) {
        float v = gelu_f(acc[i][j][p] + bj);
        if constexpr (WRITE_C) {
          int sv = (int)b2s((bf16_t)v);
          int ov = __shfl_xor(sv, 1, 64);   // neighbor column's bf16 bits
          if (!(lane & 1)) {                // even col15: store packed pair
            unsigned wrd = (unsigned)sv | ((unsigned)ov << 16);
            ast32(&C[(size_t)(rbase + p) * NDIM + col], wrd);
          }
        }
        if constexpr (COLSUM) cs += v;
      }
    }
    if constexpr (COLSUM) {
      cs += __shfl_xor(cs, 16, 64);
      cs += __shfl_xor(cs, 32, 64);
      if (lane < 16) atomicAdd(&hsum[col], cs);   // device-scope, at MALL
    }
  }
}

// Persistent kernel: head -> gemm1 -> gemm2+colsum -> gemv -> fourier,
// separated by bare counter barriers (zero cache maintenance).
__global__ __launch_bounds__(NTHR, 2) void fused_all(
    const float* __restrict__ sources, const float* __restrict__ r,
    const float* __restrict__ W1, const float* __restrict__ b1,
    const float* __restrict__ W2, const float* __restrict__ b2,
    const float* __restrict__ W3, const float* __restrict__ b3,
    const float* __restrict__ W4, const float* __restrict__ b4,
    const float* __restrict__ Wb, const float* __restrict__ bb,
    bf16_t* __restrict__ h1b, bf16_t* __restrict__ h2b,
    float* __restrict__ hsum, float* __restrict__ Wbigf,
    float* __restrict__ bsum, unsigned* __restrict__ bar,
    float* __restrict__ out, int N) {
  extern __shared__ __align__(16) unsigned char smem[];   // 32 KB union
  bf16_t* Asb = (bf16_t*)smem;              // gemm: 2 x 8 KB
  bf16_t* Bsb = (bf16_t*)(smem + 16384);    // gemm: 2 x 8 KB
  const int tid = threadIdx.x;

  // ---- Stage A: h1 = gelu(sources @ W1.T + b1), packed 64-bit sc1 stores --
  {
    const int QTOT = NSRC * HID / 4;        // 524288 4-elem groups
    for (int i4 = blockIdx.x * NTHR + tid; i4 < QTOT; i4 += NBLK * NTHR) {
      int s = i4 >> 8;
      int n0 = (i4 & 255) << 2;
      float4 src4 = *(const float4*)(sources + 4 * s);
      float4 bv = *(const float4*)(b1 + n0);
      float barr[4] = {bv.x, bv.y, bv.z, bv.w};
      union { unsigned short h[4]; u64 u; } pk;
#pragma unroll
      for (int jj = 0; jj < 4; ++jj) {
        float4 w = *(const float4*)(W1 + 4 * (n0 + jj));
        float z = src4.x * w.x + src4.y * w.y + src4.z * w.z + src4.w * w.w +
                  barr[jj];
        pk.h[jj] = b2s((bf16_t)gelu_f(z));
      }
      ast64(h1b + (size_t)i4 * 4, pk.u);
    }
  }
  grid_bar(bar, NBLK * 1);

  // XCD-swizzled tile mapping (perf heuristic only; correctness-independent):
  int tm, tn;
  {
    const int b = blockIdx.x;
    const int xcd = b & 7, j = b >> 3;            // j: 0..63
    tm = ((xcd >> 1) * 8 + (j >> 3)) * 64;        // 32 M-tiles
    tn = ((xcd & 1) * 8 + (j & 7)) * 64;          // 16 N-tiles
  }

  // ---- Stage B: h2 = gelu(h1 @ W2^T + b2) ----
  gemm_stage<true, false>(h1b, W2, b2, h2b, nullptr, Asb, Bsb, tm, tn);
  grid_bar(bar, NBLK * 2);

  // ---- Stage C: hsum += colsum(gelu(h2 @ W3^T + b3)) ----
  gemm_stage<false, true>(h2b, W3, b3, nullptr, hsum, Asb, Bsb, tm, tn);
  grid_bar(bar, NBLK * 3);

  // ---- Stage D: wsum = W4 @ hsum + S*b4 -> Wbigf (fp32, sc1); bsum ----
  for (int vb = blockIdx.x; vb <= 1024; vb += NBLK) {
    if (vb == 1024) {
      float a = 0.0f;
      float w0 = Wb[0], w1 = Wb[1], w2 = Wb[2], w3 = Wb[3];
      for (int s = tid; s < NSRC; s += NTHR) {
        float4 src = *(const float4*)(sources + 4 * s);
        a += src.x * w0 + src.y * w1 + src.z * w2 + src.w * w3;
      }
#pragma unroll
      for (int off = 32; off; off >>= 1) a += __shfl_down(a, off, 64);
      float* wred = (float*)smem;
      if ((tid & 63) == 0) wred[tid >> 6] = a;
      __syncthreads();
      if (tid == 0)
        astf(bsum, wred[0] + wred[1] + wred[2] + wred[3] + (float)NSRC * bb[0]);
    } else {
      int o = vb * 4 + (tid >> 6);
      int lane = tid & 63;
      const float* row = W4 + (size_t)o * HID;
      float acc = 0.0f;
#pragma unroll
      for (int t = 0; t < 4; ++t) {
        float4 rv = *(const float4*)(row + t * 256 + lane * 4);
        union { u64 u[2]; float4 f; } hx;
        hx.u[0] = ald64(hsum + t * 256 + lane * 4);
        hx.u[1] = ald64(hsum + t * 256 + lane * 4 + 2);
        acc = fmaf(rv.x, hx.f.x, acc);
        acc = fmaf(rv.y, hx.f.y, acc);
        acc = fmaf(rv.z, hx.f.z, acc);
        acc = fmaf(rv.w, hx.f.w, acc);
      }
#pragma unroll
      for (int off = 32; off; off >>= 1) acc += __shfl_down(acc, off, 64);
      if (lane == 0) {
        float val = acc + (float)NSRC * b4[o];
        int c = o >> 10, i5 = (o >> 5) & 31, j5 = o & 31;
        int m = i5 + (((c == 1) || (c == 3)) ? 32 : 0);
        int k = j5 + (((c == 1) || (c == 2)) ? 32 : 0);
        astf(&Wbigf[m * 64 + k], val);
      }
    }
  }
  grid_bar(bar, NBLK * 4);

  // ---- Stage E: out[n] = bsum + x(n)^T (Wbig z(n)) ----
  {
    bf16_t* Ws = (bf16_t*)smem;           // 64 x FSTR
    bf16_t* Zs = Ws + 64 * FSTR;
    bf16_t* Xs = Zs + 64 * FSTR;          // total 27648 B <= 32 KB
    const int wave = tid >> 6;
    const int lane = tid & 63;
    const int nF = (N + 63) >> 6;
    const float bs = aldf(bsum);
    bool wloaded = false;
    for (int vb = blockIdx.x; vb < nF; vb += NBLK) {
      __syncthreads();   // previous iteration's LDS readers done
      if (!wloaded) {    // stage ALL of Wbig fp32 -> bf16 LDS (16 floats/thr)
#pragma unroll
        for (int jj = 0; jj < 4; ++jj) {
          union { u64 u[2]; f32x4 f; } wv;
          wv.u[0] = ald64(Wbigf + 16 * tid + 4 * jj);
          wv.u[1] = ald64(Wbigf + 16 * tid + 4 * jj + 2);
          int wrow = tid >> 2, wcol = (tid & 3) * 16 + jj * 4;
          bf16x4 o4 = {(bf16_t)wv.f[0], (bf16_t)wv.f[1],
                       (bf16_t)wv.f[2], (bf16_t)wv.f[3]};
          *(bf16x4*)(Ws + wrow * FSTR + wcol) = o4;
        }
        wloaded = true;
      }
      {
        const int p = tid >> 2, q = tid & 3;
        int n = vb * 64 + p;
        if (n >= N) n = N - 1;
        // angle = 2*pi * a * (r/10)  ->  revolutions = a * (r*0.1);
        // v_sin/v_cos take revolutions after v_fract range-reduction.
        float rx = r[2 * n] * 0.1f, ry = r[2 * n + 1] * 0.1f;
        float a = (float)(q + 1);
        float f1x = __builtin_amdgcn_fractf(a * rx);
        float f4x = __builtin_amdgcn_fractf(4.0f * rx);
        float f1y = __builtin_amdgcn_fractf(a * ry);
        float f4y = __builtin_amdgcn_fractf(4.0f * ry);
        float s1x = __builtin_amdgcn_sinf(f1x), c1x = __builtin_amdgcn_cosf(f1x);
        float s4x = __builtin_amdgcn_sinf(f4x), c4x = __builtin_amdgcn_cosf(f4x);
        float s1y = __builtin_amdgcn_sinf(f1y), c1y = __builtin_amdgcn_cosf(f1y);
        float s4y = __builtin_amdgcn_sinf(f4y), c4y = __builtin_amdgcn_cosf(f4y);
        float cxv = c1x, sxv = s1x, cyv = c1y, syv = s1y;
#pragma unroll
        for (int t = 0; t < 8; ++t) {
          int j = q + 4 * t;
          Zs[p * FSTR + j]      = (bf16_t)cyv;
          Zs[p * FSTR + 32 + j] = (bf16_t)syv;
          Xs[p * FSTR + j]      = (bf16_t)cxv;
          Xs[p * FSTR + 32 + j] = (bf16_t)sxv;
          float tc = cxv * c4x - sxv * s4x; sxv = sxv * c4x + cxv * s4x; cxv = tc;
          tc = cyv * c4y - syv * s4y; syv = syv * c4y + cyv * s4y; cyv = tc;
        }
      }
      __syncthreads();

      const int col15 = lane & 15;
      const int quad  = lane >> 4;
      const int q8    = quad * 8;
      f32x4 G[4] = {};
#pragma unroll
      for (int kc = 0; kc < 2; ++kc) {
        bf16x8 bz = *(const bf16x8*)(Zs + (wave * 16 + col15) * FSTR + kc * 32 + q8);
#pragma unroll
        for (int mt = 0; mt < 4; ++mt) {
          bf16x8 af = *(const bf16x8*)(Ws + (mt * 16 + col15) * FSTR + kc * 32 + q8);
          G[mt] = __builtin_amdgcn_mfma_f32_16x16x32_bf16(af, bz, G[mt], 0, 0, 0);
        }
      }

      const int pt = wave * 16 + col15;
      float s = 0.0f;
#pragma unroll
      for (int mt = 0; mt < 4; ++mt) {
        bf16x4 xv = *(const bf16x4*)(Xs + pt * FSTR + mt * 16 + quad * 4);
        s += (float)xv[0] * G[mt][0] + (float)xv[1] * G[mt][1] +
             (float)xv[2] * G[mt][2] + (float)xv[3] * G[mt][3];
      }
      s += __shfl_xor(s, 16, 64);
      s += __shfl_xor(s, 32, 64);
      if (lane < 16) {
        int n2 = vb * 64 + pt;
        if (n2 >= N) n2 = N - 1;
        out[n2] = s + bs;
      }
    }
  }
}

extern "C" void kernel_launch(void* const* d_in, const int* in_sizes, int n_in,
                              void* d_out, int out_size, void* d_ws, size_t ws_size,
                              hipStream_t stream) {
  const float* sources = (const float*)d_in[0];
  const float* r   = (const float*)d_in[1];
  const float* W1  = (const float*)d_in[2];
  const float* b1  = (const float*)d_in[3];
  const float* W2  = (const float*)d_in[4];
  const float* b2  = (const float*)d_in[5];
  const float* W3  = (const float*)d_in[6];
  const float* b3  = (const float*)d_in[7];
  const float* W4  = (const float*)d_in[8];
  const float* b4  = (const float*)d_in[9];
  const float* Wb  = (const float*)d_in[10];
  const float* bb  = (const float*)d_in[11];
  float* out = (float*)d_out;

  char* ws = (char*)d_ws;
  bf16_t* h1b  = (bf16_t*)(ws);                         // 4 MB
  bf16_t* h2b  = (bf16_t*)(ws + (4 << 20));             // 4 MB
  char*   ctl  = ws + (12 << 20);                       // control block (24 KB)
  float*  hsum = (float*)(ctl);                         // 4 KB   [ctl+0)
  float*  Wbigf= (float*)(ctl + 4096);                  // 16 KB  [ctl+4096..20480)
  float*  bsum = (float*)(ctl + 20480);                 // 4 B
  unsigned* bar = (unsigned*)(ctl + 20544);             // barrier counter

  int N = out_size;   // 100000 points

  // Zero hsum + Wbigf + bsum + barrier (graph-capturable; re-runs per replay).
  hipMemsetAsync(ctl, 0, 24576, stream);

  fused_all<<<NBLK, NTHR, 32768, stream>>>(
      sources, r, W1, b1, W2, b2, W3, b3, W4, b4, Wb, bb,
      h1b, h2b, hsum, Wbigf, bsum, bar, out, N);
}

// Round 7
// 159.208 us; speedup vs baseline: 1.1941x; 1.1941x over previous
//
#include <hip/hip_runtime.h>
#include <math.h>

#define NSRC 2048
#define HID  1024
#define FSTR 72     // LDS row stride (bf16) for fourier stage
#define NBLK 512    // persistent grid: 2 blocks/CU on 256 CUs (co-resident)
#define NTHR 512    // 8 waves/block -> 16 waves/CU (2x latency hiding)

typedef __bf16 bf16_t;
typedef bf16_t bf16x8 __attribute__((ext_vector_type(8)));
typedef bf16_t bf16x4 __attribute__((ext_vector_type(4)));
typedef float  f32x4  __attribute__((ext_vector_type(4)));
typedef unsigned long long u64;

__device__ __forceinline__ float gelu_f(float x) {
  float u = 0.7978845608028654f * x * (1.0f + 0.044715f * x * x);
  return 0.5f * x * (1.0f + tanhf(u));
}

__device__ __forceinline__ bf16x8 cvt8(f32x4 a, f32x4 b) {
  bf16x8 o = {(bf16_t)a[0], (bf16_t)a[1], (bf16_t)a[2], (bf16_t)a[3],
              (bf16_t)b[0], (bf16_t)b[1], (bf16_t)b[2], (bf16_t)b[3]};
  return o;
}

// ---------------- XCD-leader grid barrier (round-2 verified, 86us) --------
// Relaxed arrival counters; LAST local arrival on each XCD does ONE
// buffer_wbl2 (flush local dirty L2), bumps done, waits all XCDs flushed,
// ONE buffer_inv (drop stale lines), sets go. 8 wbl2 + 8 inv per barrier.
__device__ __forceinline__ unsigned rl(unsigned* p) {
  return __hip_atomic_load(p, __ATOMIC_RELAXED, __HIP_MEMORY_SCOPE_AGENT);
}
__device__ __forceinline__ unsigned radd(unsigned* p) {
  unsigned o = __hip_atomic_fetch_add(p, 1u, __ATOMIC_RELAXED,
                                      __HIP_MEMORY_SCOPE_AGENT);
  asm volatile("" ::"v"(o));   // force vmcnt drain: add completed before next op
  return o;
}

struct BarCtx {
  unsigned xcc, myTotal, nxcd, inited;
};

// B layout (u32 idx): [0..7]=totals  [8]=setup  [16+(p-1)*8+x]=arrive
//                     [48+(p-1)]=done  [56+(p-1)*8+x]=go    (p=1..4)
__device__ void grid_bar(unsigned* B, BarCtx& c, int phase) {
  __syncthreads();                 // all block stores vmcnt-drained, in L2
  if (threadIdx.x == 0) {
    if (!c.inited) {               // finish startup census (overlapped w/ stage A)
      while (rl(B + 8) < NBLK) __builtin_amdgcn_s_sleep(2);
      unsigned nx = 0, mt = 0;
      for (int x = 0; x < 8; ++x) {
        unsigned t = rl(B + x);
        nx += (t != 0);
        if ((unsigned)x == c.xcc) mt = t;
      }
      c.myTotal = mt; c.nxcd = nx; c.inited = 1;
    }
    unsigned old = radd(B + 16 + (phase - 1) * 8 + c.xcc);
    if (old == c.myTotal - 1) {    // last local arrival: I flush this XCD
      asm volatile("buffer_wbl2 sc1\n\ts_waitcnt vmcnt(0)" ::: "memory");
      radd(B + 48 + (phase - 1));
      while (rl(B + 48 + (phase - 1)) < c.nxcd) __builtin_amdgcn_s_sleep(2);
      asm volatile("buffer_inv sc1\n\ts_waitcnt vmcnt(0)" ::: "memory");
      __hip_atomic_store(B + 56 + (phase - 1) * 8 + c.xcc, 1u,
                         __ATOMIC_RELAXED, __HIP_MEMORY_SCOPE_AGENT);
    } else {
      while (rl(B + 56 + (phase - 1) * 8 + c.xcc) == 0)
        __builtin_amdgcn_s_sleep(2);
    }
  }
  __syncthreads();
}

// C = gelu(A @ Bf^T + bias). A (2048,1024) bf16; Bf (1024,1024) fp32
// read-only input, converted to bf16 during LDS staging (identical cast).
// BM=BN=64, BK=64, 8 waves: wave w owns rows (w&1)*32..+32, cols (w>>1)*16.
// Rolling-register prefetch + LDS double-buffer, one barrier per k-step,
// XOR bank swizzle. All loads/stores PLAIN (L2-cached; barriers flush/inv).
template <bool WRITE_C, bool COLSUM>
__device__ __forceinline__ void gemm_stage(
    const bf16_t* __restrict__ A, const float* __restrict__ Bf,
    const float* __restrict__ bias, bf16_t* __restrict__ C,
    float* __restrict__ hsum, bf16_t* Asb, bf16_t* Bsb, int tm, int tn) {
  const int K = 1024, NDIM = 1024;
  const int tid  = threadIdx.x;
  const int wave = tid >> 6;
  const int lane = tid & 63;
  const int wm = (wave & 1) * 32;
  const int wn = (wave >> 1) * 16;

  // staging: thread t owns 16B chunk t of each 64x64 tile (512 chunks).
  // chunk t -> row t>>3, phys chunk t&7; fetch logical lc = pc ^ (row&7).
  const int row0 = tid >> 3;           // 0..63
  const int pc   = tid & 7;
  const int lc   = pc ^ (row0 & 7);
  const bf16_t* gA = A + (size_t)(tm + row0) * K + lc * 8;
  const float*  gB = Bf + (size_t)(tn + row0) * K + lc * 8;

  const int col15 = lane & 15;
  const int quad  = lane >> 4;
  const int rsw   = col15 & 7;
  f32x4 acc[2] = {};

  // prologue: k0=0 tile into regs
  bf16x8 ra  = *(const bf16x8*)(gA);
  f32x4  rb0 = *(const f32x4*)(gB);
  f32x4  rb1 = *(const f32x4*)(gB + 4);

#define COMPUTE_TILE(b)                                                        \
  do {                                                                         \
    _Pragma("unroll")                                                          \
    for (int s = 0; s < 2; ++s) {                                              \
      const int pck = (s * 4 + quad) ^ rsw;                                    \
      bf16x8 a0 = *(const bf16x8*)(&Asb[(b)*4096 + (wm + col15) * 64 + pck * 8]);      \
      bf16x8 a1 = *(const bf16x8*)(&Asb[(b)*4096 + (wm + 16 + col15) * 64 + pck * 8]); \
      bf16x8 b0 = *(const bf16x8*)(&Bsb[(b)*4096 + (wn + col15) * 64 + pck * 8]);      \
      acc[0] = __builtin_amdgcn_mfma_f32_16x16x32_bf16(a0, b0, acc[0], 0, 0, 0);       \
      acc[1] = __builtin_amdgcn_mfma_f32_16x16x32_bf16(a1, b0, acc[1], 0, 0, 0);       \
    }                                                                          \
  } while (0)

  for (int k0 = 0; k0 < K; k0 += 64) {
    const int buf = (k0 >> 6) & 1;
    __syncthreads();   // prev compute of `buf` done across all waves
    bf16x8 na; f32x4 nb0, nb1;
    const bool more = (k0 + 64 < K);
    if (more) {        // issue next-tile loads BEFORE ds_writes (rolling regs)
      na  = *(const bf16x8*)(gA + k0 + 64);
      nb0 = *(const f32x4*)(gB + k0 + 64);
      nb1 = *(const f32x4*)(gB + k0 + 68);
    }
    *(bf16x8*)(&Asb[buf * 4096 + tid * 8]) = ra;
    *(bf16x8*)(&Bsb[buf * 4096 + tid * 8]) = cvt8(rb0, rb1);
    if (more) { ra = na; rb0 = nb0; rb1 = nb1; }
    if (k0 > 0) COMPUTE_TILE(buf ^ 1);
  }
  __syncthreads();
  COMPUTE_TILE(1);     // 16 tiles, last buf = 15 & 1 = 1
#undef COMPUTE_TILE

  const int rq = quad * 4;
  const int col = tn + wn + col15;
  const float bj = bias[col];
  float cs = 0.0f;
#pragma unroll
  for (int i = 0; i < 2; ++i) {
    const int rbase = tm + wm + i * 16 + rq;
#pragma unroll
    for (int p = 0; p < 4; ++p) {
      float v = gelu_f(acc[i][p] + bj);
      if constexpr (WRITE_C) C[(size_t)(rbase + p) * NDIM + col] = (bf16_t)v;
      if constexpr (COLSUM) cs += v;
    }
  }
  if constexpr (COLSUM) {
    cs += __shfl_xor(cs, 16, 64);
    cs += __shfl_xor(cs, 32, 64);
    if (lane < 16) atomicAdd(&hsum[col], cs);   // device-scope, at MALL
  }
}

// Persistent kernel: head(+bsum) -> gemm1 -> gemm2+colsum -> gemv -> fourier,
// separated by XCD-leader flush barriers. 512 thr/block, 16 waves/CU.
__global__ __launch_bounds__(NTHR, 4) void fused_all(
    const float* __restrict__ sources, const float* __restrict__ r,
    const float* __restrict__ W1, const float* __restrict__ b1,
    const float* __restrict__ W2, const float* __restrict__ b2,
    const float* __restrict__ W3, const float* __restrict__ b3,
    const float* __restrict__ W4, const float* __restrict__ b4,
    const float* __restrict__ Wb, const float* __restrict__ bb,
    bf16_t* __restrict__ h1b, bf16_t* __restrict__ h2b,
    float* __restrict__ hsum, float* __restrict__ Wbigf,
    float* __restrict__ bsum, unsigned* __restrict__ bar,
    float* __restrict__ out, int N) {
  extern __shared__ __align__(16) unsigned char smem[];   // 46080 B union
  bf16_t* Asb = (bf16_t*)smem;              // gemm: 2 x 8 KB
  bf16_t* Bsb = (bf16_t*)(smem + 16384);    // gemm: 2 x 8 KB
  const int tid  = threadIdx.x;
  const int wave = tid >> 6;
  const int lane = tid & 63;

  BarCtx bc;
  {
    unsigned xcc;
    asm("s_getreg_b32 %0, hwreg(HW_REG_XCC_ID)" : "=s"(xcc));
    bc.xcc = xcc & 7; bc.inited = 0; bc.myTotal = 0; bc.nxcd = 0;
    if (tid == 0) {            // startup census; totals read at first barrier
      radd(bar + bc.xcc);      // totals[xcc]++
      radd(bar + 8);           // setup++
    }
  }

  // ---- Stage A: h1 = gelu(sources @ W1.T + b1); block 0 also does bsum ----
  {
    const int QTOT = NSRC * HID / 4;        // 524288 4-elem groups
    for (int i4 = blockIdx.x * NTHR + tid; i4 < QTOT; i4 += NBLK * NTHR) {
      int s = i4 >> 8;
      int n0 = (i4 & 255) << 2;
      float4 src4 = *(const float4*)(sources + 4 * s);
      float4 bv = *(const float4*)(b1 + n0);
      float barr[4] = {bv.x, bv.y, bv.z, bv.w};
      union { unsigned short h[4]; u64 u; } pk;
#pragma unroll
      for (int jj = 0; jj < 4; ++jj) {
        float4 w = *(const float4*)(W1 + 4 * (n0 + jj));
        float z = src4.x * w.x + src4.y * w.y + src4.z * w.z + src4.w * w.w +
                  barr[jj];
        union { bf16_t b; unsigned short s16; } cv; cv.b = (bf16_t)gelu_f(z);
        pk.h[jj] = cv.s16;
      }
      *(u64*)(h1b + (size_t)i4 * 4) = pk.u;   // plain 8B store
    }
    if (blockIdx.x == 0) {    // bsum = sum_s sources.Wb + S*bb (inputs only)
      float a = 0.0f;
      float w0 = Wb[0], w1 = Wb[1], w2 = Wb[2], w3 = Wb[3];
      for (int s = tid; s < NSRC; s += NTHR) {
        float4 src = *(const float4*)(sources + 4 * s);
        a += src.x * w0 + src.y * w1 + src.z * w2 + src.w * w3;
      }
#pragma unroll
      for (int off = 32; off; off >>= 1) a += __shfl_down(a, off, 64);
      float* wred = (float*)smem;
      if (lane == 0) wred[wave] = a;
      __syncthreads();
      if (tid == 0) {
        float v = 0.0f;
        for (int w = 0; w < 8; ++w) v += wred[w];
        bsum[0] = v + (float)NSRC * bb[0];
      }
    }
  }
  grid_bar(bar, bc, 1);

  // XCD-swizzled tile mapping (perf heuristic only; correctness-independent):
  int tm, tn;
  {
    const int b = blockIdx.x;
    const int xcd = b & 7, j = b >> 3;            // j: 0..63
    tm = ((xcd >> 1) * 8 + (j >> 3)) * 64;        // 32 M-tiles
    tn = ((xcd & 1) * 8 + (j & 7)) * 64;          // 16 N-tiles
  }

  // ---- Stage B: h2 = gelu(h1 @ W2^T + b2) ----
  gemm_stage<true, false>(h1b, W2, b2, h2b, nullptr, Asb, Bsb, tm, tn);
  grid_bar(bar, bc, 2);

  // ---- Stage C: hsum += colsum(gelu(h2 @ W3^T + b3)) ----
  gemm_stage<false, true>(h2b, W3, b3, nullptr, hsum, Asb, Bsb, tm, tn);
  grid_bar(bar, bc, 3);

  // ---- Stage D: wsum = W4 @ hsum + S*b4 -> Wbigf (fp32). One-shot:
  //      o = bid*8 + wave covers all 4096 outputs exactly. ----
  {
    int o = blockIdx.x * 8 + wave;
    const float* row = W4 + (size_t)o * HID;
    float acc = 0.0f;
#pragma unroll
    for (int t = 0; t < 4; ++t) {
      float4 rv = *(const float4*)(row + t * 256 + lane * 4);
      float4 hv = *(const float4*)(hsum + t * 256 + lane * 4);
      acc = fmaf(rv.x, hv.x, acc);
      acc = fmaf(rv.y, hv.y, acc);
      acc = fmaf(rv.z, hv.z, acc);
      acc = fmaf(rv.w, hv.w, acc);
    }
#pragma unroll
    for (int off = 32; off; off >>= 1) acc += __shfl_down(acc, off, 64);
    if (lane == 0) {
      float val = acc + (float)NSRC * b4[o];
      int c = o >> 10, i5 = (o >> 5) & 31, j5 = o & 31;
      int m = i5 + (((c == 1) || (c == 3)) ? 32 : 0);
      int k = j5 + (((c == 1) || (c == 2)) ? 32 : 0);
      Wbigf[m * 64 + k] = val;    // plain store; barrier-4 wbl2 flushes
    }
  }
  grid_bar(bar, bc, 4);

  // ---- Stage E: out[n] = bsum + x(n)^T (Wbig z(n)). Two 4-wave groups
  //      per block, each handling one 64-pt tile per iteration. Uniform
  //      iteration count + tile clamp (duplicate writes compute the same
  //      value for point N-1) so __syncthreads never diverges. ----
  {
    bf16_t* S  = (bf16_t*)smem;
    bf16_t* Ws = S;                               // 64 x FSTR (shared)
    const int g = tid >> 8;                       // group 0/1
    bf16_t* Zg = S + 64 * FSTR * (1 + 2 * g);     // per-group Z
    bf16_t* Xg = Zg + 64 * FSTR;                  // per-group X
    const int wave_g = wave & 3;
    const int col15 = lane & 15;
    const int quad  = lane >> 4;
    const int q8    = quad * 8;
    const int nF = (N + 63) >> 6;
    const float bs = bsum[0];
    const int nIter = (nF + 2 * NBLK - 1) / (2 * NBLK);
    for (int it = 0; it < nIter; ++it) {
      int tile = (it * NBLK + blockIdx.x) * 2 + g;
      if (tile >= nF) tile = nF - 1;
      __syncthreads();   // previous iteration's LDS readers done
      if (it == 0) {     // stage Wbig fp32 -> bf16 LDS (8 floats/thread)
        f32x4 w0 = *(const f32x4*)(Wbigf + 8 * tid);
        f32x4 w1 = *(const f32x4*)(Wbigf + 8 * tid + 4);
        int wrow = tid >> 3, wcol = (tid & 7) * 8;
        bf16x4 o0 = {(bf16_t)w0[0], (bf16_t)w0[1], (bf16_t)w0[2], (bf16_t)w0[3]};
        bf16x4 o1 = {(bf16_t)w1[0], (bf16_t)w1[1], (bf16_t)w1[2], (bf16_t)w1[3]};
        *(bf16x4*)(Ws + wrow * FSTR + wcol) = o0;
        *(bf16x4*)(Ws + wrow * FSTR + wcol + 4) = o1;
      }
      {
        const int p = (tid & 255) >> 2, q = tid & 3;
        int n = tile * 64 + p;
        if (n >= N) n = N - 1;
        // angle = 2*pi * a * (r/10)  ->  revolutions = a * (r*0.1);
        // v_sin/v_cos take revolutions after v_fract range-reduction.
        float rx = r[2 * n] * 0.1f, ry = r[2 * n + 1] * 0.1f;
        float a = (float)(q + 1);
        float f1x = __builtin_amdgcn_fractf(a * rx);
        float f4x = __builtin_amdgcn_fractf(4.0f * rx);
        float f1y = __builtin_amdgcn_fractf(a * ry);
        float f4y = __builtin_amdgcn_fractf(4.0f * ry);
        float s1x = __builtin_amdgcn_sinf(f1x), c1x = __builtin_amdgcn_cosf(f1x);
        float s4x = __builtin_amdgcn_sinf(f4x), c4x = __builtin_amdgcn_cosf(f4x);
        float s1y = __builtin_amdgcn_sinf(f1y), c1y = __builtin_amdgcn_cosf(f1y);
        float s4y = __builtin_amdgcn_sinf(f4y), c4y = __builtin_amdgcn_cosf(f4y);
        float cxv = c1x, sxv = s1x, cyv = c1y, syv = s1y;
#pragma unroll
        for (int t = 0; t < 8; ++t) {
          int j = q + 4 * t;
          Zg[p * FSTR + j]      = (bf16_t)cyv;
          Zg[p * FSTR + 32 + j] = (bf16_t)syv;
          Xg[p * FSTR + j]      = (bf16_t)cxv;
          Xg[p * FSTR + 32 + j] = (bf16_t)sxv;
          float tc = cxv * c4x - sxv * s4x; sxv = sxv * c4x + cxv * s4x; cxv = tc;
          tc = cyv * c4y - syv * s4y; syv = syv * c4y + cyv * s4y; cyv = tc;
        }
      }
      __syncthreads();

      f32x4 G[4] = {};
#pragma unroll
      for (int kc = 0; kc < 2; ++kc) {
        bf16x8 bz = *(const bf16x8*)(Zg + (wave_g * 16 + col15) * FSTR + kc * 32 + q8);
#pragma unroll
        for (int mt = 0; mt < 4; ++mt) {
          bf16x8 af = *(const bf16x8*)(Ws + (mt * 16 + col15) * FSTR + kc * 32 + q8);
          G[mt] = __builtin_amdgcn_mfma_f32_16x16x32_bf16(af, bz, G[mt], 0, 0, 0);
        }
      }

      const int pt = wave_g * 16 + col15;
      float s = 0.0f;
#pragma unroll
      for (int mt = 0; mt < 4; ++mt) {
        bf16x4 xv = *(const bf16x4*)(Xg + pt * FSTR + mt * 16 + quad * 4);
        s += (float)xv[0] * G[mt][0] + (float)xv[1] * G[mt][1] +
             (float)xv[2] * G[mt][2] + (float)xv[3] * G[mt][3];
      }
      s += __shfl_xor(s, 16, 64);
      s += __shfl_xor(s, 32, 64);
      if (lane < 16) {
        int n2 = tile * 64 + pt;
        if (n2 >= N) n2 = N - 1;
        out[n2] = s + bs;
      }
    }
  }
}

extern "C" void kernel_launch(void* const* d_in, const int* in_sizes, int n_in,
                              void* d_out, int out_size, void* d_ws, size_t ws_size,
                              hipStream_t stream) {
  const float* sources = (const float*)d_in[0];
  const float* r   = (const float*)d_in[1];
  const float* W1  = (const float*)d_in[2];
  const float* b1  = (const float*)d_in[3];
  const float* W2  = (const float*)d_in[4];
  const float* b2  = (const float*)d_in[5];
  const float* W3  = (const float*)d_in[6];
  const float* b3  = (const float*)d_in[7];
  const float* W4  = (const float*)d_in[8];
  const float* b4  = (const float*)d_in[9];
  const float* Wb  = (const float*)d_in[10];
  const float* bb  = (const float*)d_in[11];
  float* out = (float*)d_out;

  char* ws = (char*)d_ws;
  bf16_t* h1b  = (bf16_t*)(ws);                         // 4 MB
  bf16_t* h2b  = (bf16_t*)(ws + (4 << 20));             // 4 MB
  char*   ctl  = ws + (12 << 20);                       // control block (24 KB)
  float*  hsum = (float*)(ctl);                         // 4 KB   [ctl+0)
  float*  Wbigf= (float*)(ctl + 4096);                  // 16 KB  [ctl+4096..20480)
  float*  bsum = (float*)(ctl + 20480);                 // 4 B
  unsigned* bar = (unsigned*)(ctl + 20544);             // barrier state (~352 B)

  int N = out_size;   // 100000 points

  // Zero hsum + Wbigf + bsum + barrier (graph-capturable; re-runs per replay).
  hipMemsetAsync(ctl, 0, 24576, stream);

  fused_all<<<NBLK, NTHR, 46080, stream>>>(
      sources, r, W1, b1, W2, b2, W3, b3, W4, b4, Wb, bb,
      h1b, h2b, hsum, Wbigf, bsum, bar, out, N);
}

// Round 8
// 134.198 us; speedup vs baseline: 1.4167x; 1.1864x over previous
//
#include <hip/hip_runtime.h>
#include <math.h>

#define NSRC 2048
#define HID  1024
#define NORD 32
#define FSTR 72   // LDS row stride (bf16) for fourier kernel

typedef __bf16 bf16_t;
typedef bf16_t bf16x8 __attribute__((ext_vector_type(8)));
typedef bf16_t bf16x4 __attribute__((ext_vector_type(4)));
typedef float  f32x4  __attribute__((ext_vector_type(4)));
typedef unsigned long long u64;

__device__ __forceinline__ float gelu_f(float x) {
  float u = 0.7978845608028654f * x * (1.0f + 0.044715f * x * x);
  return 0.5f * x * (1.0f + tanhf(u));
}

__device__ __forceinline__ bf16x8 cvt8(f32x4 a, f32x4 b) {
  bf16x8 o = {(bf16_t)a[0], (bf16_t)a[1], (bf16_t)a[2], (bf16_t)a[3],
              (bf16_t)b[0], (bf16_t)b[1], (bf16_t)b[2], (bf16_t)b[3]};
  return o;
}

// Slim head: h1 = gelu(sources @ W1.T + b1) only (W2/W3 conversion deleted —
// GEMMs now read fp32 weights directly). One-shot grid, 4 bf16 packed per
// thread into one 8 B store.
__global__ __launch_bounds__(256) void head_kernel(
    const float* __restrict__ sources, const float* __restrict__ W1,
    const float* __restrict__ b1, bf16_t* __restrict__ h1b) {
  int i4 = blockIdx.x * 256 + threadIdx.x;   // 0..524287 (4-elem groups)
  int s = i4 >> 8;
  int n0 = (i4 & 255) << 2;
  float4 src4 = *(const float4*)(sources + 4 * s);
  float4 bv   = *(const float4*)(b1 + n0);
  float barr[4] = {bv.x, bv.y, bv.z, bv.w};
  union { unsigned short h[4]; u64 u; } pk;
#pragma unroll
  for (int jj = 0; jj < 4; ++jj) {
    float4 w = *(const float4*)(W1 + 4 * (n0 + jj));
    float z = src4.x * w.x + src4.y * w.y + src4.z * w.z + src4.w * w.w +
              barr[jj];
    union { bf16_t b; unsigned short s16; } cv; cv.b = (bf16_t)gelu_f(z);
    pk.h[jj] = cv.s16;
  }
  *(u64*)(h1b + (size_t)i4 * 4) = pk.u;
}

// C = gelu(A @ B^T + bias). A (2048,1024) bf16, B (1024,1024) FP32 input
// converted to bf16 during LDS staging (identical cast to the old W2b/W3b).
// BM=BN=64, BK=64. Register-prefetch + LDS double-buffer (32 KB), ONE
// barrier per k-step (round-0 verified structure). Grid 512 = 2 blocks/CU.
// XOR swizzle (phys chunk = logical ^ (row&7)): frag ds_read_b128 <=2-way.
template <bool WRITE_C, bool COLSUM>
__global__ __launch_bounds__(256) void gemm_bf16_mfma(
    const bf16_t* __restrict__ A, const float* __restrict__ B,
    const float* __restrict__ bias, bf16_t* __restrict__ C,
    float* __restrict__ hsum) {
  const int K = 1024, NDIM = 1024;
  __shared__ bf16_t As[2][64 * 64];   // 8 KB each
  __shared__ bf16_t Bs[2][64 * 64];
  const int tid  = threadIdx.x;
  const int wave = tid >> 6;
  const int lane = tid & 63;
  const int tm = blockIdx.y * 64;
  const int tn = blockIdx.x * 64;
  const int wm = (wave & 1) * 32;
  const int wn = (wave >> 1) * 32;

  // staging: thread t owns 16B chunks {t, t+256} of each 64x64 tile.
  // chunk c -> row c>>3, phys chunk c&7; fetch logical lc = pc ^ (row&7);
  // chunk t+256 is row+32, same row&7 -> same lc.
  const int row0 = tid >> 3;           // 0..31
  const int pc   = tid & 7;
  const int lc   = pc ^ (row0 & 7);
  const bf16_t* gA = A + (size_t)(tm + row0) * K + lc * 8;
  const float*  gB = B + (size_t)(tn + row0) * K + lc * 8;

  const int col15 = lane & 15;
  const int quad  = lane >> 4;
  const int rsw   = col15 & 7;
  f32x4 acc[2][2] = {};

  // prologue: load k0=0 into regs
  bf16x8 ra0 = *(const bf16x8*)(gA);
  bf16x8 ra1 = *(const bf16x8*)(gA + (size_t)32 * K);
  f32x4 rb00 = *(const f32x4*)(gB);
  f32x4 rb01 = *(const f32x4*)(gB + 4);
  f32x4 rb10 = *(const f32x4*)(gB + (size_t)32 * K);
  f32x4 rb11 = *(const f32x4*)(gB + (size_t)32 * K + 4);

#define COMPUTE_TILE(b)                                                        \
  do {                                                                         \
    _Pragma("unroll")                                                          \
    for (int s = 0; s < 2; ++s) {                                              \
      const int pck = (s * 4 + quad) ^ rsw;                                    \
      bf16x8 a0 = *(const bf16x8*)(&As[b][(wm + col15) * 64 + pck * 8]);       \
      bf16x8 a1 = *(const bf16x8*)(&As[b][(wm + 16 + col15) * 64 + pck * 8]);  \
      bf16x8 b0 = *(const bf16x8*)(&Bs[b][(wn + col15) * 64 + pck * 8]);       \
      bf16x8 b1 = *(const bf16x8*)(&Bs[b][(wn + 16 + col15) * 64 + pck * 8]);  \
      acc[0][0] = __builtin_amdgcn_mfma_f32_16x16x32_bf16(a0, b0, acc[0][0], 0, 0, 0); \
      acc[0][1] = __builtin_amdgcn_mfma_f32_16x16x32_bf16(a0, b1, acc[0][1], 0, 0, 0); \
      acc[1][0] = __builtin_amdgcn_mfma_f32_16x16x32_bf16(a1, b0, acc[1][0], 0, 0, 0); \
      acc[1][1] = __builtin_amdgcn_mfma_f32_16x16x32_bf16(a1, b1, acc[1][1], 0, 0, 0); \
    }                                                                          \
  } while (0)

  for (int k0 = 0; k0 < K; k0 += 64) {
    const int buf = (k0 >> 6) & 1;
    __syncthreads();   // prev compute of `buf` done across all waves
    *(bf16x8*)(&As[buf][tid * 8])         = ra0;
    *(bf16x8*)(&As[buf][(tid + 256) * 8]) = ra1;
    *(bf16x8*)(&Bs[buf][tid * 8])         = cvt8(rb00, rb01);
    *(bf16x8*)(&Bs[buf][(tid + 256) * 8]) = cvt8(rb10, rb11);
    if (k0 + 64 < K) {   // issue next tile's loads; consumed next iteration
      ra0  = *(const bf16x8*)(gA + k0 + 64);
      ra1  = *(const bf16x8*)(gA + (size_t)32 * K + k0 + 64);
      rb00 = *(const f32x4*)(gB + k0 + 64);
      rb01 = *(const f32x4*)(gB + k0 + 68);
      rb10 = *(const f32x4*)(gB + (size_t)32 * K + k0 + 64);
      rb11 = *(const f32x4*)(gB + (size_t)32 * K + k0 + 68);
    }
    if (k0 > 0) COMPUTE_TILE(buf ^ 1);   // compute tile written last iter
  }
  __syncthreads();     // last write visible across waves
  COMPUTE_TILE(1);     // K/64 = 16 tiles, last buf = 15 & 1 = 1
#undef COMPUTE_TILE

  const int rq = quad * 4;
#pragma unroll
  for (int j = 0; j < 2; ++j) {
    const int col = tn + wn + j * 16 + col15;
    const float bj = bias[col];
    float cs = 0.0f;
#pragma unroll
    for (int i = 0; i < 2; ++i) {
      const int rbase = tm + wm + i * 16 + rq;
#pragma unroll
      for (int p = 0; p < 4; ++p) {
        float v = gelu_f(acc[i][j][p] + bj);
        if (WRITE_C) C[(size_t)(rbase + p) * NDIM + col] = (bf16_t)v;
        if (COLSUM) cs += v;
      }
    }
    if (COLSUM) {
      cs += __shfl_xor(cs, 16, 64);
      cs += __shfl_xor(cs, 32, 64);
      if (lane < 16) atomicAdd(&hsum[col], cs);
    }
  }
}

// wsum[o] = W4[o,:].hsum + S*b4[o], emitted as bf16 into packed Wbig[64][64]:
//   o=(c,i,j): m = i + 32*(c==1||c==3), k = j + 32*(c==1||c==2)
// block 1024: bsum = (sum_s sources[s].Wb) + S*bb
__global__ __launch_bounds__(256) void gemv_kernel(
    const float* __restrict__ W4, const float* __restrict__ hsum,
    const float* __restrict__ b4, bf16_t* __restrict__ Wbig,
    const float* __restrict__ sources, const float* __restrict__ Wb,
    const float* __restrict__ bb, float* __restrict__ bsum) {
  if (blockIdx.x == 1024) {
    float a = 0.0f;
    float w0 = Wb[0], w1 = Wb[1], w2 = Wb[2], w3 = Wb[3];
    for (int s = threadIdx.x; s < NSRC; s += 256) {
      float4 src = *(const float4*)(sources + 4 * s);
      a += src.x * w0 + src.y * w1 + src.z * w2 + src.w * w3;
    }
#pragma unroll
    for (int off = 32; off; off >>= 1) a += __shfl_down(a, off, 64);
    __shared__ float wred[4];
    if ((threadIdx.x & 63) == 0) wred[threadIdx.x >> 6] = a;
    __syncthreads();
    if (threadIdx.x == 0)
      bsum[0] = wred[0] + wred[1] + wred[2] + wred[3] + (float)NSRC * bb[0];
    return;
  }
  int o = blockIdx.x * 4 + (threadIdx.x >> 6);   // 0..4095
  int lane = threadIdx.x & 63;
  const float* row = W4 + (size_t)o * HID;
  float acc = 0.0f;
#pragma unroll
  for (int t = 0; t < 4; ++t) {
    float4 rv = *(const float4*)(row + t * 256 + lane * 4);
    float4 hv = *(const float4*)(hsum + t * 256 + lane * 4);
    acc = fmaf(rv.x, hv.x, acc);
    acc = fmaf(rv.y, hv.y, acc);
    acc = fmaf(rv.z, hv.z, acc);
    acc = fmaf(rv.w, hv.w, acc);
  }
#pragma unroll
  for (int off = 32; off; off >>= 1) acc += __shfl_down(acc, off, 64);
  if (lane == 0) {
    float val = acc + (float)NSRC * b4[o];
    int c = o >> 10, i5 = (o >> 5) & 31, j5 = o & 31;
    int m = i5 + (((c == 1) || (c == 3)) ? 32 : 0);
    int k = j5 + (((c == 1) || (c == 2)) ? 32 : 0);
    Wbig[m * 64 + k] = (bf16_t)val;
  }
}

// out[n] = bsum + x(n)^T (Wbig z(n)),  x=[cx;sx], z=[cy;sy] (64-dim each).
// Trig via hw v_fract + v_sin/v_cos (input in revolutions: a * r/10).
__global__ __launch_bounds__(256) void fourier_mfma(
    const float* __restrict__ r, const bf16_t* __restrict__ Wbig,
    const float* __restrict__ bsum, float* __restrict__ out, int N) {
  __shared__ bf16_t Ws[64 * FSTR];
  __shared__ bf16_t Zs[64 * FSTR];   // [pt][k]
  __shared__ bf16_t Xs[64 * FSTR];   // [pt][m]
  const int tid  = threadIdx.x;
  const int wave = tid >> 6;
  const int lane = tid & 63;

  {
    const bf16x8* Wg = (const bf16x8*)Wbig;
    bf16x8 w0 = Wg[2 * tid], w1 = Wg[2 * tid + 1];
    int wrow = tid >> 2;
    int wcol = (tid & 3) * 16;
    *(bf16x8*)(Ws + wrow * FSTR + wcol) = w0;
    *(bf16x8*)(Ws + wrow * FSTR + wcol + 8) = w1;
  }

  {
    const int p = tid >> 2, q = tid & 3;
    int n = blockIdx.x * 64 + p;
    if (n >= N) n = N - 1;
    // angle = 2*pi * a * (r/10)  ->  revolutions = a * (r*0.1);
    // v_sin/v_cos take revolutions after v_fract range-reduction.
    float rx = r[2 * n] * 0.1f, ry = r[2 * n + 1] * 0.1f;
    float a = (float)(q + 1);
    float f1x = __builtin_amdgcn_fractf(a * rx);
    float f4x = __builtin_amdgcn_fractf(4.0f * rx);
    float f1y = __builtin_amdgcn_fractf(a * ry);
    float f4y = __builtin_amdgcn_fractf(4.0f * ry);
    float s1x = __builtin_amdgcn_sinf(f1x), c1x = __builtin_amdgcn_cosf(f1x);
    float s4x = __builtin_amdgcn_sinf(f4x), c4x = __builtin_amdgcn_cosf(f4x);
    float s1y = __builtin_amdgcn_sinf(f1y), c1y = __builtin_amdgcn_cosf(f1y);
    float s4y = __builtin_amdgcn_sinf(f4y), c4y = __builtin_amdgcn_cosf(f4y);
    float cxv = c1x, sxv = s1x, cyv = c1y, syv = s1y;
#pragma unroll
    for (int t = 0; t < 8; ++t) {
      int j = q + 4 * t;
      Zs[p * FSTR + j]      = (bf16_t)cyv;
      Zs[p * FSTR + 32 + j] = (bf16_t)syv;
      Xs[p * FSTR + j]      = (bf16_t)cxv;
      Xs[p * FSTR + 32 + j] = (bf16_t)sxv;
      float tc = cxv * c4x - sxv * s4x; sxv = sxv * c4x + cxv * s4x; cxv = tc;
      tc = cyv * c4y - syv * s4y; syv = syv * c4y + cyv * s4y; cyv = tc;
    }
  }
  __syncthreads();

  const int col15 = lane & 15;
  const int quad  = lane >> 4;
  const int q8    = quad * 8;
  f32x4 G[4] = {};
#pragma unroll
  for (int kc = 0; kc < 2; ++kc) {
    bf16x8 bz = *(const bf16x8*)(Zs + (wave * 16 + col15) * FSTR + kc * 32 + q8);
#pragma unroll
    for (int mt = 0; mt < 4; ++mt) {
      bf16x8 af = *(const bf16x8*)(Ws + (mt * 16 + col15) * FSTR + kc * 32 + q8);
      G[mt] = __builtin_amdgcn_mfma_f32_16x16x32_bf16(af, bz, G[mt], 0, 0, 0);
    }
  }

  const int pt = wave * 16 + col15;
  float s = 0.0f;
#pragma unroll
  for (int mt = 0; mt < 4; ++mt) {
    bf16x4 xv = *(const bf16x4*)(Xs + pt * FSTR + mt * 16 + quad * 4);
    s += (float)xv[0] * G[mt][0] + (float)xv[1] * G[mt][1] +
         (float)xv[2] * G[mt][2] + (float)xv[3] * G[mt][3];
  }
  s += __shfl_xor(s, 16, 64);
  s += __shfl_xor(s, 32, 64);
  if (lane < 16) {
    int n2 = blockIdx.x * 64 + pt;
    if (n2 >= N) n2 = N - 1;
    out[n2] = s + bsum[0];
  }
}

extern "C" void kernel_launch(void* const* d_in, const int* in_sizes, int n_in,
                              void* d_out, int out_size, void* d_ws, size_t ws_size,
                              hipStream_t stream) {
  const float* sources = (const float*)d_in[0];
  const float* r   = (const float*)d_in[1];
  const float* W1  = (const float*)d_in[2];
  const float* b1  = (const float*)d_in[3];
  const float* W2  = (const float*)d_in[4];
  const float* b2  = (const float*)d_in[5];
  const float* W3  = (const float*)d_in[6];
  const float* b3  = (const float*)d_in[7];
  const float* W4  = (const float*)d_in[8];
  const float* b4  = (const float*)d_in[9];
  const float* Wb  = (const float*)d_in[10];
  const float* bb  = (const float*)d_in[11];
  float* out = (float*)d_out;

  char* ws = (char*)d_ws;
  bf16_t* h1b  = (bf16_t*)(ws);                         // 4 MB
  bf16_t* h2b  = (bf16_t*)(ws + (4 << 20));             // 4 MB
  float*  hsum = (float*)(ws + (8 << 20));              // 4 KB
  bf16_t* Wbig = (bf16_t*)(ws + (8 << 20) + 4096);      // 8 KB
  float*  bsum = (float*)(ws + (8 << 20) + 16384);      // 4 B

  int N = out_size;                       // 100000 points

  // Zero hsum (accumulated via atomics; re-runs every replay).
  hipMemsetAsync(hsum, 0, 4096, stream);

  head_kernel<<<NSRC * HID / 1024, 256, 0, stream>>>(sources, W1, b1, h1b);
  gemm_bf16_mfma<true, false><<<dim3(HID / 64, NSRC / 64), 256, 0, stream>>>(
      h1b, W2, b2, h2b, nullptr);
  gemm_bf16_mfma<false, true><<<dim3(HID / 64, NSRC / 64), 256, 0, stream>>>(
      h2b, W3, b3, nullptr, hsum);
  gemv_kernel<<<1025, 256, 0, stream>>>(W4, hsum, b4, Wbig, sources, Wb, bb, bsum);
  fourier_mfma<<<(N + 63) / 64, 256, 0, stream>>>(r, Wbig, bsum, out, N);
}

// Round 9
// 125.987 us; speedup vs baseline: 1.5090x; 1.0652x over previous
//
#include <hip/hip_runtime.h>
#include <math.h>

#define NSRC 2048
#define HID  1024
#define NORD 32
#define FSTR 72   // LDS row stride (bf16) for fourier kernel

typedef __bf16 bf16_t;
typedef bf16_t bf16x8 __attribute__((ext_vector_type(8)));
typedef bf16_t bf16x4 __attribute__((ext_vector_type(4)));
typedef float  f32x4  __attribute__((ext_vector_type(4)));

__device__ __forceinline__ float gelu_f(float x) {
  float u = 0.7978845608028654f * x * (1.0f + 0.044715f * x * x);
  return 0.5f * x * (1.0f + tanhf(u));
}

// Fused: h1 = gelu(sources @ W1.T + b1) -> bf16; W2/W3 fp32 -> bf16; zero hsum.
__global__ __launch_bounds__(256) void head_kernel(
    const float* __restrict__ sources, const float* __restrict__ W1,
    const float* __restrict__ b1, bf16_t* __restrict__ h1b,
    const float* __restrict__ W2, const float* __restrict__ W3,
    bf16_t* __restrict__ W2b, bf16_t* __restrict__ W3b,
    float* __restrict__ hsum) {
  int idx = blockIdx.x * 256 + threadIdx.x;          // 2M total
  if (blockIdx.x == 0) {
    for (int c = threadIdx.x; c < HID; c += 256) hsum[c] = 0.0f;
  }
  const int HALF = HID * HID / 4;                     // 262144 float4s
  if (idx < 2 * HALF) {
    const float* src = (idx < HALF) ? W2 : W3;
    bf16_t* dst = (idx < HALF) ? W2b : W3b;
    int j = (idx < HALF) ? idx : idx - HALF;
    float4 v = ((const float4*)src)[j];
    bf16x4 o = {(bf16_t)v.x, (bf16_t)v.y, (bf16_t)v.z, (bf16_t)v.w};
    ((bf16x4*)dst)[j] = o;
  }
  int s = idx >> 10;
  int n = idx & (HID - 1);
  float4 src4 = *(const float4*)(sources + 4 * s);
  float4 w    = *(const float4*)(W1 + 4 * n);
  float z = src4.x * w.x + src4.y * w.y + src4.z * w.z + src4.w * w.w + b1[n];
  h1b[idx] = (bf16_t)gelu_f(z);
}

// C = gelu(A @ B^T + bias). A (2048,1024), B (1024,1024), bf16 NT.
// BM=BN=64, BK=64. Register-prefetch + LDS double-buffer (32 KB), ONE
// barrier per k-step. Grid 512 = 2 blocks/CU. XOR swizzle (phys chunk =
// logical ^ (row&7)): fragment ds_read_b128 <=2-way on banks (free).
template <bool WRITE_C, bool COLSUM>
__global__ __launch_bounds__(256) void gemm_bf16_mfma(
    const bf16_t* __restrict__ A, const bf16_t* __restrict__ B,
    const float* __restrict__ bias, bf16_t* __restrict__ C,
    float* __restrict__ hsum) {
  const int K = 1024, NDIM = 1024;
  __shared__ bf16_t As[2][64 * 64];   // 8 KB each
  __shared__ bf16_t Bs[2][64 * 64];
  const int tid  = threadIdx.x;
  const int wave = tid >> 6;
  const int lane = tid & 63;
  const int tm = blockIdx.y * 64;
  const int tn = blockIdx.x * 64;
  const int wm = (wave & 1) * 32;
  const int wn = (wave >> 1) * 32;

  // staging: thread t owns 16B chunks {t, t+256} of each 64x64 tile.
  // chunk c -> row c>>3, phys chunk c&7; fetch logical lc = pc ^ (row&7);
  // chunk t+256 is row+32, same row&7 -> same lc.
  const int row0 = tid >> 3;           // 0..31
  const int pc   = tid & 7;
  const int lc   = pc ^ (row0 & 7);
  const bf16_t* gA = A + (size_t)(tm + row0) * K + lc * 8;
  const bf16_t* gB = B + (size_t)(tn + row0) * K + lc * 8;

  const int col15 = lane & 15;
  const int quad  = lane >> 4;
  const int rsw   = col15 & 7;
  f32x4 acc[2][2] = {};

  // prologue: load k0=0 into regs
  bf16x8 ra0 = *(const bf16x8*)(gA);
  bf16x8 ra1 = *(const bf16x8*)(gA + (size_t)32 * K);
  bf16x8 rb0 = *(const bf16x8*)(gB);
  bf16x8 rb1 = *(const bf16x8*)(gB + (size_t)32 * K);

#define COMPUTE_TILE(b)                                                        \
  do {                                                                         \
    _Pragma("unroll")                                                          \
    for (int s = 0; s < 2; ++s) {                                              \
      const int pck = (s * 4 + quad) ^ rsw;                                    \
      bf16x8 a0 = *(const bf16x8*)(&As[b][(wm + col15) * 64 + pck * 8]);       \
      bf16x8 a1 = *(const bf16x8*)(&As[b][(wm + 16 + col15) * 64 + pck * 8]);  \
      bf16x8 b0 = *(const bf16x8*)(&Bs[b][(wn + col15) * 64 + pck * 8]);       \
      bf16x8 b1 = *(const bf16x8*)(&Bs[b][(wn + 16 + col15) * 64 + pck * 8]);  \
      acc[0][0] = __builtin_amdgcn_mfma_f32_16x16x32_bf16(a0, b0, acc[0][0], 0, 0, 0); \
      acc[0][1] = __builtin_amdgcn_mfma_f32_16x16x32_bf16(a0, b1, acc[0][1], 0, 0, 0); \
      acc[1][0] = __builtin_amdgcn_mfma_f32_16x16x32_bf16(a1, b0, acc[1][0], 0, 0, 0); \
      acc[1][1] = __builtin_amdgcn_mfma_f32_16x16x32_bf16(a1, b1, acc[1][1], 0, 0, 0); \
    }                                                                          \
  } while (0)

  for (int k0 = 0; k0 < K; k0 += 64) {
    const int buf = (k0 >> 6) & 1;
    __syncthreads();   // prev compute of `buf` done across all waves
    *(bf16x8*)(&As[buf][tid * 8])         = ra0;
    *(bf16x8*)(&As[buf][(tid + 256) * 8]) = ra1;
    *(bf16x8*)(&Bs[buf][tid * 8])         = rb0;
    *(bf16x8*)(&Bs[buf][(tid + 256) * 8]) = rb1;
    if (k0 + 64 < K) {   // issue next tile's loads; consumed next iteration
      ra0 = *(const bf16x8*)(gA + k0 + 64);
      ra1 = *(const bf16x8*)(gA + (size_t)32 * K + k0 + 64);
      rb0 = *(const bf16x8*)(gB + k0 + 64);
      rb1 = *(const bf16x8*)(gB + (size_t)32 * K + k0 + 64);
    }
    if (k0 > 0) COMPUTE_TILE(buf ^ 1);   // compute tile written last iter
  }
  __syncthreads();     // last write visible across waves
  COMPUTE_TILE(1);     // K/64 = 16 tiles, last buf = 15 & 1 = 1
#undef COMPUTE_TILE

  const int rq = quad * 4;
#pragma unroll
  for (int j = 0; j < 2; ++j) {
    const int col = tn + wn + j * 16 + col15;
    const float bj = bias[col];
    float cs = 0.0f;
#pragma unroll
    for (int i = 0; i < 2; ++i) {
      const int rbase = tm + wm + i * 16 + rq;
#pragma unroll
      for (int p = 0; p < 4; ++p) {
        float v = gelu_f(acc[i][j][p] + bj);
        if (WRITE_C) C[(size_t)(rbase + p) * NDIM + col] = (bf16_t)v;
        if (COLSUM) cs += v;
      }
    }
    if (COLSUM) {
      cs += __shfl_xor(cs, 16, 64);
      cs += __shfl_xor(cs, 32, 64);
      if (lane < 16) atomicAdd(&hsum[col], cs);
    }
  }
}

// wsum[o] = W4[o,:].hsum + S*b4[o], emitted as bf16 into packed Wbig[64][64]:
//   o=(c,i,j): m = i + 32*(c==1||c==3), k = j + 32*(c==1||c==2)
// block 1024: bsum = (sum_s sources[s].Wb) + S*bb
__global__ __launch_bounds__(256) void gemv_kernel(
    const float* __restrict__ W4, const float* __restrict__ hsum,
    const float* __restrict__ b4, bf16_t* __restrict__ Wbig,
    const float* __restrict__ sources, const float* __restrict__ Wb,
    const float* __restrict__ bb, float* __restrict__ bsum) {
  if (blockIdx.x == 1024) {
    float a = 0.0f;
    float w0 = Wb[0], w1 = Wb[1], w2 = Wb[2], w3 = Wb[3];
    for (int s = threadIdx.x; s < NSRC; s += 256) {
      float4 src = *(const float4*)(sources + 4 * s);
      a += src.x * w0 + src.y * w1 + src.z * w2 + src.w * w3;
    }
#pragma unroll
    for (int off = 32; off; off >>= 1) a += __shfl_down(a, off, 64);
    __shared__ float wred[4];
    if ((threadIdx.x & 63) == 0) wred[threadIdx.x >> 6] = a;
    __syncthreads();
    if (threadIdx.x == 0)
      bsum[0] = wred[0] + wred[1] + wred[2] + wred[3] + (float)NSRC * bb[0];
    return;
  }
  int o = blockIdx.x * 4 + (threadIdx.x >> 6);   // 0..4095
  int lane = threadIdx.x & 63;
  const float* row = W4 + (size_t)o * HID;
  float acc = 0.0f;
#pragma unroll
  for (int t = 0; t < 4; ++t) {
    float4 rv = *(const float4*)(row + t * 256 + lane * 4);
    float4 hv = *(const float4*)(hsum + t * 256 + lane * 4);
    acc = fmaf(rv.x, hv.x, acc);
    acc = fmaf(rv.y, hv.y, acc);
    acc = fmaf(rv.z, hv.z, acc);
    acc = fmaf(rv.w, hv.w, acc);
  }
#pragma unroll
  for (int off = 32; off; off >>= 1) acc += __shfl_down(acc, off, 64);
  if (lane == 0) {
    float val = acc + (float)NSRC * b4[o];
    int c = o >> 10, i5 = (o >> 5) & 31, j5 = o & 31;
    int m = i5 + (((c == 1) || (c == 3)) ? 32 : 0);
    int k = j5 + (((c == 1) || (c == 2)) ? 32 : 0);
    Wbig[m * 64 + k] = (bf16_t)val;
  }
}

// out[n] = bsum + x(n)^T (Wbig z(n)),  x=[cx;sx], z=[cy;sy] (64-dim each).
// Trig via hw v_fract + v_sin/v_cos (input in revolutions: a * r/10) —
// validated rounds 6-8 (absmax unchanged at 128).
__global__ __launch_bounds__(256) void fourier_mfma(
    const float* __restrict__ r, const bf16_t* __restrict__ Wbig,
    const float* __restrict__ bsum, float* __restrict__ out, int N) {
  __shared__ bf16_t Ws[64 * FSTR];
  __shared__ bf16_t Zs[64 * FSTR];   // [pt][k]
  __shared__ bf16_t Xs[64 * FSTR];   // [pt][m]
  const int tid  = threadIdx.x;
  const int wave = tid >> 6;
  const int lane = tid & 63;

  {
    const bf16x8* Wg = (const bf16x8*)Wbig;
    bf16x8 w0 = Wg[2 * tid], w1 = Wg[2 * tid + 1];
    int wrow = tid >> 2;
    int wcol = (tid & 3) * 16;
    *(bf16x8*)(Ws + wrow * FSTR + wcol) = w0;
    *(bf16x8*)(Ws + wrow * FSTR + wcol + 8) = w1;
  }

  {
    const int p = tid >> 2, q = tid & 3;
    int n = blockIdx.x * 64 + p;
    if (n >= N) n = N - 1;
    // angle = 2*pi * a * (r/10)  ->  revolutions = a * (r*0.1);
    // v_sin/v_cos take revolutions after v_fract range-reduction.
    float rx = r[2 * n] * 0.1f, ry = r[2 * n + 1] * 0.1f;
    float a = (float)(q + 1);
    float f1x = __builtin_amdgcn_fractf(a * rx);
    float f4x = __builtin_amdgcn_fractf(4.0f * rx);
    float f1y = __builtin_amdgcn_fractf(a * ry);
    float f4y = __builtin_amdgcn_fractf(4.0f * ry);
    float s1x = __builtin_amdgcn_sinf(f1x), c1x = __builtin_amdgcn_cosf(f1x);
    float s4x = __builtin_amdgcn_sinf(f4x), c4x = __builtin_amdgcn_cosf(f4x);
    float s1y = __builtin_amdgcn_sinf(f1y), c1y = __builtin_amdgcn_cosf(f1y);
    float s4y = __builtin_amdgcn_sinf(f4y), c4y = __builtin_amdgcn_cosf(f4y);
    float cxv = c1x, sxv = s1x, cyv = c1y, syv = s1y;
#pragma unroll
    for (int t = 0; t < 8; ++t) {
      int j = q + 4 * t;
      Zs[p * FSTR + j]      = (bf16_t)cyv;
      Zs[p * FSTR + 32 + j] = (bf16_t)syv;
      Xs[p * FSTR + j]      = (bf16_t)cxv;
      Xs[p * FSTR + 32 + j] = (bf16_t)sxv;
      float tc = cxv * c4x - sxv * s4x; sxv = sxv * c4x + cxv * s4x; cxv = tc;
      tc = cyv * c4y - syv * s4y; syv = syv * c4y + cyv * s4y; cyv = tc;
    }
  }
  __syncthreads();

  const int col15 = lane & 15;
  const int quad  = lane >> 4;
  const int q8    = quad * 8;
  f32x4 G[4] = {};
#pragma unroll
  for (int kc = 0; kc < 2; ++kc) {
    bf16x8 bz = *(const bf16x8*)(Zs + (wave * 16 + col15) * FSTR + kc * 32 + q8);
#pragma unroll
    for (int mt = 0; mt < 4; ++mt) {
      bf16x8 af = *(const bf16x8*)(Ws + (mt * 16 + col15) * FSTR + kc * 32 + q8);
      G[mt] = __builtin_amdgcn_mfma_f32_16x16x32_bf16(af, bz, G[mt], 0, 0, 0);
    }
  }

  const int pt = wave * 16 + col15;
  float s = 0.0f;
#pragma unroll
  for (int mt = 0; mt < 4; ++mt) {
    bf16x4 xv = *(const bf16x4*)(Xs + pt * FSTR + mt * 16 + quad * 4);
    s += (float)xv[0] * G[mt][0] + (float)xv[1] * G[mt][1] +
         (float)xv[2] * G[mt][2] + (float)xv[3] * G[mt][3];
  }
  s += __shfl_xor(s, 16, 64);
  s += __shfl_xor(s, 32, 64);
  if (lane < 16) {
    int n2 = blockIdx.x * 64 + pt;
    if (n2 >= N) n2 = N - 1;
    out[n2] = s + bsum[0];
  }
}

extern "C" void kernel_launch(void* const* d_in, const int* in_sizes, int n_in,
                              void* d_out, int out_size, void* d_ws, size_t ws_size,
                              hipStream_t stream) {
  const float* sources = (const float*)d_in[0];
  const float* r   = (const float*)d_in[1];
  const float* W1  = (const float*)d_in[2];
  const float* b1  = (const float*)d_in[3];
  const float* W2  = (const float*)d_in[4];
  const float* b2  = (const float*)d_in[5];
  const float* W3  = (const float*)d_in[6];
  const float* b3  = (const float*)d_in[7];
  const float* W4  = (const float*)d_in[8];
  const float* b4  = (const float*)d_in[9];
  const float* Wb  = (const float*)d_in[10];
  const float* bb  = (const float*)d_in[11];
  float* out = (float*)d_out;

  char* ws = (char*)d_ws;
  bf16_t* h1b  = (bf16_t*)(ws);                         // 4 MB
  bf16_t* h2b  = (bf16_t*)(ws + (4 << 20));             // 4 MB
  bf16_t* W2b  = (bf16_t*)(ws + (8 << 20));             // 2 MB
  bf16_t* W3b  = (bf16_t*)(ws + (10 << 20));            // 2 MB
  float*  hsum = (float*)(ws + (12 << 20));             // 4 KB
  bf16_t* Wbig = (bf16_t*)(ws + (12 << 20) + 4096);     // 8 KB
  float*  bsum = (float*)(ws + (12 << 20) + 16384);     // 4 B

  int N = out_size;                       // 100000 points

  head_kernel<<<NSRC * HID / 256, 256, 0, stream>>>(
      sources, W1, b1, h1b, W2, W3, W2b, W3b, hsum);
  gemm_bf16_mfma<true, false><<<dim3(HID / 64, NSRC / 64), 256, 0, stream>>>(
      h1b, W2b, b2, h2b, nullptr);
  gemm_bf16_mfma<false, true><<<dim3(HID / 64, NSRC / 64), 256, 0, stream>>>(
      h2b, W3b, b3, nullptr, hsum);
  gemv_kernel<<<1025, 256, 0, stream>>>(W4, hsum, b4, Wbig, sources, Wb, bb, bsum);
  fourier_mfma<<<(N + 63) / 64, 256, 0, stream>>>(r, Wbig, bsum, out, N);
}